// Round 1
// baseline (1199.882 us; speedup 1.0000x reference)
//
#include <hip/hip_runtime.h>
#include <math.h>

#define HSZ 50000
#define INSZ 50000
#define NNZc 800000
#define BSZ 8
#define TSZ 32

// ---------------- CSR build ----------------

__global__ void hist_kernel(const int* __restrict__ hh_idx, const int* __restrict__ ih_idx,
                            int* __restrict__ hh_cnt, int* __restrict__ ih_cnt) {
    int i = blockIdx.x * blockDim.x + threadIdx.x;
    if (i < NNZc) {
        atomicAdd(&hh_cnt[hh_idx[i]], 1);
    } else if (i < 2 * NNZc) {
        atomicAdd(&ih_cnt[ih_idx[i - NNZc]], 1);
    }
}

// One block per matrix (blockIdx.x in {0,1}); single-block chunked Hillis-Steele scan.
__global__ void scan_kernel(const int* __restrict__ cnt0, int* __restrict__ ptr0, int* __restrict__ fill0,
                            const int* __restrict__ cnt1, int* __restrict__ ptr1, int* __restrict__ fill1,
                            int n) {
    const int* cnt = blockIdx.x ? cnt1 : cnt0;
    int* ptr  = blockIdx.x ? ptr1 : ptr0;
    int* fill = blockIdx.x ? fill1 : fill0;
    __shared__ int sm[1024];
    __shared__ int carry_s;
    int tid = threadIdx.x;
    if (tid == 0) carry_s = 0;
    __syncthreads();
    for (int base = 0; base < n; base += 1024) {
        int idx = base + tid;
        int v = (idx < n) ? cnt[idx] : 0;
        sm[tid] = v;
        __syncthreads();
        int x = v;
        for (int off = 1; off < 1024; off <<= 1) {
            int y = (tid >= off) ? sm[tid - off] : 0;
            __syncthreads();
            x += y;
            sm[tid] = x;
            __syncthreads();
        }
        int excl = x - v + carry_s;  // exclusive scan + carry from previous chunks
        if (idx < n) { ptr[idx] = excl; fill[idx] = excl; }
        __syncthreads();             // everyone reads carry_s before it is updated
        if (tid == 1023) carry_s += x;  // x at tid==1023 is the chunk total
        __syncthreads();
    }
    if (tid == 0) ptr[n] = carry_s;
}

__global__ void scatter_kernel(const int* __restrict__ hh_idx, const float* __restrict__ hh_v,
                               const int* __restrict__ ih_idx, const float* __restrict__ ih_v,
                               int* __restrict__ hh_fill, int* __restrict__ ih_fill,
                               int* __restrict__ hh_cols, float* __restrict__ hh_vals,
                               int* __restrict__ ih_cols, float* __restrict__ ih_vals) {
    int i = blockIdx.x * blockDim.x + threadIdx.x;
    if (i < NNZc) {
        int r = hh_idx[i];
        int c = hh_idx[NNZc + i];
        int pos = atomicAdd(&hh_fill[r], 1);
        hh_cols[pos] = c;
        hh_vals[pos] = hh_v[i];
    } else if (i < 2 * NNZc) {
        int k = i - NNZc;
        int r = ih_idx[k];
        int c = ih_idx[NNZc + k];
        int pos = atomicAdd(&ih_fill[r], 1);
        ih_cols[pos] = c;
        ih_vals[pos] = ih_v[k];
    }
}

// ---------------- x transpose: (B,T,IN) -> (T,IN,B) ----------------

__global__ void transpose_x(const float* __restrict__ x, float* __restrict__ xT) {
    int u = blockIdx.x * blockDim.x + threadIdx.x;  // u = t*IN + i
    if (u >= TSZ * INSZ) return;
    float v[BSZ];
#pragma unroll
    for (int b = 0; b < BSZ; ++b) v[b] = x[(size_t)b * TSZ * INSZ + u];
    float4 v0 = make_float4(v[0], v[1], v[2], v[3]);
    float4 v1 = make_float4(v[4], v[5], v[6], v[7]);
    float4* dst = (float4*)(xT + (size_t)u * 8);
    dst[0] = v0;
    dst[1] = v1;
}

// ---------------- ih precompute: ihc[t][r][b] = sum_j v_j * xT[t][col_j][b] ----------------

__global__ void ihc_kernel_xT(const int* __restrict__ ptr, const int* __restrict__ cols,
                              const float* __restrict__ vals,
                              const float* __restrict__ xT, float* __restrict__ ihc) {
    size_t gid = (size_t)blockIdx.x * blockDim.x + threadIdx.x;  // ((t*H + r)*8 + b)
    if (gid >= (size_t)TSZ * HSZ * 8) return;
    int b = (int)(gid & 7);
    int u = (int)(gid >> 3);  // t*H + r
    int t = u / HSZ;
    int r = u - t * HSZ;
    int s = ptr[r], e = ptr[r + 1];
    const float* xp = xT + (size_t)t * INSZ * 8 + b;
    float acc = 0.f;
    for (int j = s; j < e; ++j) acc += vals[j] * xp[(size_t)cols[j] * 8];
    ihc[gid] = acc;
}

__global__ void ihc_kernel_direct(const int* __restrict__ ptr, const int* __restrict__ cols,
                                  const float* __restrict__ vals,
                                  const float* __restrict__ x, float* __restrict__ ihc) {
    size_t gid = (size_t)blockIdx.x * blockDim.x + threadIdx.x;
    if (gid >= (size_t)TSZ * HSZ * 8) return;
    int b = (int)(gid & 7);
    int u = (int)(gid >> 3);
    int t = u / HSZ;
    int r = u - t * HSZ;
    int s = ptr[r], e = ptr[r + 1];
    const float* xp = x + (size_t)b * TSZ * INSZ + (size_t)t * INSZ;
    float acc = 0.f;
    for (int j = s; j < e; ++j) acc += vals[j] * xp[cols[j]];
    ihc[gid] = acc;
}

// ---------------- sequential step: h_new = tanh(hh @ h + bias + ihc[t]) ----------------

__global__ void step_kernel(const int* __restrict__ ptr, const int* __restrict__ cols,
                            const float* __restrict__ vals, const float* __restrict__ bias,
                            const float* __restrict__ ihc_t, const float* __restrict__ h_in,
                            float* __restrict__ h_out, float* __restrict__ out, int t) {
    int gid = blockIdx.x * blockDim.x + threadIdx.x;  // r*8 + b
    if (gid >= HSZ * 8) return;
    int b = gid & 7;
    int r = gid >> 3;
    int s = ptr[r], e = ptr[r + 1];
    float acc = 0.f;
    for (int j = s; j < e; ++j) acc += vals[j] * h_in[(size_t)cols[j] * 8 + b];
    float pre = acc + bias[r] + ihc_t[gid];
    float h = tanhf(pre);
    h_out[gid] = h;
    out[((size_t)b * TSZ + t) * HSZ + r] = h;
}

// ---------------- launch ----------------

static inline size_t align256(size_t x) { return (x + 255) & ~(size_t)255; }

extern "C" void kernel_launch(void* const* d_in, const int* in_sizes, int n_in,
                              void* d_out, int out_size, void* d_ws, size_t ws_size,
                              hipStream_t stream) {
    const float* x          = (const float*)d_in[0];
    const float* hh_values  = (const float*)d_in[1];
    const float* hh_bias    = (const float*)d_in[2];
    const float* ih_values  = (const float*)d_in[3];
    const int*   hh_indices = (const int*)d_in[4];
    const int*   ih_indices = (const int*)d_in[5];
    float* out = (float*)d_out;

    const size_t SZ_XT   = (size_t)TSZ * INSZ * BSZ * 4;   // 51.2 MB
    const size_t SZ_IHC  = (size_t)TSZ * HSZ * BSZ * 4;    // 51.2 MB
    const size_t SZ_HBUF = (size_t)2 * HSZ * BSZ * 4;      // 3.2 MB
    const size_t SZ_PTR  = align256((size_t)(HSZ + 1) * 4);
    const size_t SZ_CNT  = align256((size_t)HSZ * 4);
    const size_t SZ_COLS = (size_t)NNZc * 4;
    const size_t SZ_VALS = (size_t)NNZc * 4;

    const size_t perMat = SZ_PTR + 2 * SZ_CNT + SZ_COLS + SZ_VALS;
    const size_t needB  = SZ_IHC + SZ_HBUF + 2 * perMat;
    const size_t needA  = needB + SZ_XT;
    const bool useXT = (ws_size >= needA);

    char* ws = (char*)d_ws;
    float* xT = nullptr;
    if (useXT) { xT = (float*)ws; ws += SZ_XT; }
    float* ihc  = (float*)ws; ws += SZ_IHC;
    float* hbuf = (float*)ws; ws += SZ_HBUF;
    int*   hh_ptr  = (int*)ws; ws += SZ_PTR;
    int*   hh_fill = (int*)ws; ws += SZ_CNT;
    int*   hh_cnt  = (int*)ws; ws += SZ_CNT;
    int*   hh_cols = (int*)ws; ws += SZ_COLS;
    float* hh_vals = (float*)ws; ws += SZ_VALS;
    int*   ih_ptr  = (int*)ws; ws += SZ_PTR;
    int*   ih_fill = (int*)ws; ws += SZ_CNT;
    int*   ih_cnt  = (int*)ws; ws += SZ_CNT;
    int*   ih_cols = (int*)ws; ws += SZ_COLS;
    float* ih_vals = (float*)ws; ws += SZ_VALS;

    // zero histogram counters and h0
    hipMemsetAsync(hh_cnt, 0, (size_t)HSZ * 4, stream);
    hipMemsetAsync(ih_cnt, 0, (size_t)HSZ * 4, stream);
    hipMemsetAsync(hbuf, 0, (size_t)HSZ * BSZ * 4, stream);

    // CSR build
    int histBlocks = (2 * NNZc + 255) / 256;
    hist_kernel<<<histBlocks, 256, 0, stream>>>(hh_indices, ih_indices, hh_cnt, ih_cnt);
    scan_kernel<<<2, 1024, 0, stream>>>(hh_cnt, hh_ptr, hh_fill, ih_cnt, ih_ptr, ih_fill, HSZ);
    scatter_kernel<<<histBlocks, 256, 0, stream>>>(hh_indices, hh_values, ih_indices, ih_values,
                                                   hh_fill, ih_fill, hh_cols, hh_vals,
                                                   ih_cols, ih_vals);

    // ih precompute for all timesteps (fully parallel)
    size_t nIhc = (size_t)TSZ * HSZ * 8;
    int ihcBlocks = (int)((nIhc + 255) / 256);
    if (useXT) {
        transpose_x<<<(TSZ * INSZ + 255) / 256, 256, 0, stream>>>(x, xT);
        ihc_kernel_xT<<<ihcBlocks, 256, 0, stream>>>(ih_ptr, ih_cols, ih_vals, xT, ihc);
    } else {
        ihc_kernel_direct<<<ihcBlocks, 256, 0, stream>>>(ih_ptr, ih_cols, ih_vals, x, ihc);
    }

    // sequential recurrence
    int stepBlocks = (HSZ * 8 + 255) / 256;
    for (int t = 0; t < TSZ; ++t) {
        float* hin  = hbuf + (size_t)(t & 1) * HSZ * 8;
        float* hout = hbuf + (size_t)((t + 1) & 1) * HSZ * 8;
        const float* ihc_t = ihc + (size_t)t * HSZ * 8;
        step_kernel<<<stepBlocks, 256, 0, stream>>>(hh_ptr, hh_cols, hh_vals, hh_bias,
                                                    ihc_t, hin, hout, out, t);
    }
}

// Round 2
// 928.615 us; speedup vs baseline: 1.2921x; 1.2921x over previous
//
#include <hip/hip_runtime.h>
#include <math.h>

#define HSZ 50000
#define INSZ 50000
#define NNZc 800000
#define BSZ 8
#define TSZ 32
#define NCHUNK 49   // ceil(HSZ/1024)

// ---------------- CSR build ----------------

__global__ void hist_kernel(const int* __restrict__ hh_idx, const int* __restrict__ ih_idx,
                            int* __restrict__ hh_cnt, int* __restrict__ ih_cnt) {
    int i = blockIdx.x * blockDim.x + threadIdx.x;
    if (i < NNZc) {
        atomicAdd(&hh_cnt[hh_idx[i]], 1);
    } else if (i < 2 * NNZc) {
        atomicAdd(&ih_cnt[ih_idx[i - NNZc]], 1);
    }
}

// Per-chunk exclusive scan; chunk totals to partials[mat*64 + chunk].
__global__ void scanA_kernel(const int* __restrict__ cnt_hh, const int* __restrict__ cnt_ih,
                             int* __restrict__ ptr_hh, int* __restrict__ ptr_ih,
                             int* __restrict__ partials) {
    const int* cnt = blockIdx.y ? cnt_ih : cnt_hh;
    int* ptr = blockIdx.y ? ptr_ih : ptr_hh;
    __shared__ int sm[1024];
    int tid = threadIdx.x;
    int idx = blockIdx.x * 1024 + tid;
    int v = (idx < HSZ) ? cnt[idx] : 0;
    sm[tid] = v;
    __syncthreads();
    int x = v;
    for (int off = 1; off < 1024; off <<= 1) {
        int y = (tid >= off) ? sm[tid - off] : 0;
        __syncthreads();
        x += y;
        sm[tid] = x;
        __syncthreads();
    }
    if (idx < HSZ) ptr[idx] = x - v;
    if (tid == 1023) partials[blockIdx.y * 64 + blockIdx.x] = x;
}

// One wave scans the chunk totals (exclusive), both matrices.
__global__ void scanB_kernel(int* __restrict__ partials) {
    int lane = threadIdx.x;
    for (int m = 0; m < 2; ++m) {
        int v = (lane < NCHUNK) ? partials[m * 64 + lane] : 0;
        int orig = v;
        for (int off = 1; off < 64; off <<= 1) {
            int y = __shfl_up(v, off, 64);
            if (lane >= off) v += y;
        }
        if (lane < NCHUNK) partials[m * 64 + lane] = v - orig;
    }
}

__global__ void scanC_kernel(int* __restrict__ ptr_hh, int* __restrict__ fill_hh,
                             int* __restrict__ ptr_ih, int* __restrict__ fill_ih,
                             const int* __restrict__ partials) {
    int mat = blockIdx.y;
    int* ptr  = mat ? ptr_ih : ptr_hh;
    int* fill = mat ? fill_ih : fill_hh;
    int i = blockIdx.x * 256 + threadIdx.x;
    if (i < HSZ) {
        int v = ptr[i] + partials[mat * 64 + (i >> 10)];
        ptr[i] = v;
        fill[i] = v;
    }
    if (i == 0) ptr[HSZ] = NNZc;
}

// Scatter into packed (col, val) pairs: one 8B load per nnz downstream.
__global__ void scatter_kernel(const int* __restrict__ hh_idx, const float* __restrict__ hh_v,
                               const int* __restrict__ ih_idx, const float* __restrict__ ih_v,
                               int* __restrict__ hh_fill, int* __restrict__ ih_fill,
                               float2* __restrict__ hh_cv, float2* __restrict__ ih_cv) {
    int i = blockIdx.x * blockDim.x + threadIdx.x;
    if (i < NNZc) {
        int r = hh_idx[i];
        int c = hh_idx[NNZc + i];
        int pos = atomicAdd(&hh_fill[r], 1);
        hh_cv[pos] = make_float2(__int_as_float(c), hh_v[i]);
    } else if (i < 2 * NNZc) {
        int k = i - NNZc;
        int r = ih_idx[k];
        int c = ih_idx[NNZc + k];
        int pos = atomicAdd(&ih_fill[r], 1);
        ih_cv[pos] = make_float2(__int_as_float(c), ih_v[k]);
    }
}

// ---------------- transpose: x (B,T,IN) -> X2 (IN, 256) where col = t*8+b ----------------

__global__ void transpose_x2(const float* __restrict__ x, float* __restrict__ X2) {
    extern __shared__ float tile[];   // 64 * 257 floats
    int i0 = blockIdx.x * 64;
    int tid = threadIdx.x;
    int il = tid & 63, tg = tid >> 6;
    for (int k = 0; k < 64; ++k) {
        int tb = k * 4 + tg;                 // 0..255
        int t = tb >> 3, b = tb & 7;
        int i = i0 + il;
        float v = (i < INSZ) ? x[((size_t)b * TSZ + t) * INSZ + i] : 0.f;
        tile[il * 257 + tb] = v;             // stride 257: conflict-free
    }
    __syncthreads();
    for (int k = 0; k < 64; ++k) {
        int i = i0 + k;
        if (i < INSZ) X2[(size_t)i * 256 + tid] = tile[k * 257 + tid];
    }
}

// ---------------- ihc: one wave per row, 1KB coalesced X2 row reads ----------------
// ihc layout: float4 array, element [(t*2+q)*HSZ + r] holds b = q*4..q*4+3 for (t,r).
// lane covers tb = lane*4..lane*4+3  =>  t*2+q == lane. Bias folded in here.

__global__ void ihc_kernel(const int* __restrict__ ptr, const float2* __restrict__ cv,
                           const float* __restrict__ bias, const float4* __restrict__ X2,
                           float4* __restrict__ ihc) {
    int r = (blockIdx.x << 2) + (threadIdx.x >> 6);
    int lane = threadIdx.x & 63;
    if (r >= HSZ) return;
    int s = ptr[r], e = ptr[r + 1];
    s = __builtin_amdgcn_readfirstlane(s);   // wave-uniform -> scalar loop, s_load colval
    e = __builtin_amdgcn_readfirstlane(e);
    float4 acc = make_float4(0.f, 0.f, 0.f, 0.f);
    for (int j = s; j < e; ++j) {
        float2 c_v = cv[j];
        int c = __float_as_int(c_v.x);
        float v = c_v.y;
        float4 xv = X2[((size_t)c << 6) + lane];
        acc.x = fmaf(v, xv.x, acc.x);
        acc.y = fmaf(v, xv.y, acc.y);
        acc.z = fmaf(v, xv.z, acc.z);
        acc.w = fmaf(v, xv.w, acc.w);
    }
    float bb = bias[r];
    acc.x += bb; acc.y += bb; acc.z += bb; acc.w += bb;
    ihc[(size_t)lane * HSZ + r] = acc;
}

// ---------------- recurrence step ----------------

__device__ __forceinline__ float fast_tanh(float x) {
    float e = __expf(2.0f * x);
    return 1.0f - __fdividef(2.0f, e + 1.0f);
}

__global__ void step_kernel(const int* __restrict__ ptr, const float2* __restrict__ cv,
                            const float4* __restrict__ ihc_t, const float4* __restrict__ h_in,
                            float4* __restrict__ h_out, float* __restrict__ out, int t) {
    int item = blockIdx.x * 256 + threadIdx.x;   // item = r*2 + q ; q selects b-half
    if (item >= 2 * HSZ) return;
    int r = item >> 1, q = item & 1;
    int s = ptr[r], e = ptr[r + 1];
    float4 acc = ihc_t[q * HSZ + r];             // bias already folded in
    for (int j = s; j < e; ++j) {
        float2 c_v = cv[j];
        int c = __float_as_int(c_v.x);
        float v = c_v.y;
        float4 hv = h_in[((size_t)c << 1) + q];  // 2 lanes/row share one 32B line
        acc.x = fmaf(v, hv.x, acc.x);
        acc.y = fmaf(v, hv.y, acc.y);
        acc.z = fmaf(v, hv.z, acc.z);
        acc.w = fmaf(v, hv.w, acc.w);
    }
    float4 h;
    h.x = fast_tanh(acc.x);
    h.y = fast_tanh(acc.y);
    h.z = fast_tanh(acc.z);
    h.w = fast_tanh(acc.w);
    h_out[item] = h;                             // h layout (H, 2×float4), contiguous
    int b0 = q << 2;
    out[((size_t)(b0 + 0) * TSZ + t) * HSZ + r] = h.x;
    out[((size_t)(b0 + 1) * TSZ + t) * HSZ + r] = h.y;
    out[((size_t)(b0 + 2) * TSZ + t) * HSZ + r] = h.z;
    out[((size_t)(b0 + 3) * TSZ + t) * HSZ + r] = h.w;
}

// ---------------- launch ----------------

static inline size_t align256(size_t x) { return (x + 255) & ~(size_t)255; }

extern "C" void kernel_launch(void* const* d_in, const int* in_sizes, int n_in,
                              void* d_out, int out_size, void* d_ws, size_t ws_size,
                              hipStream_t stream) {
    const float* x          = (const float*)d_in[0];
    const float* hh_values  = (const float*)d_in[1];
    const float* hh_bias    = (const float*)d_in[2];
    const float* ih_values  = (const float*)d_in[3];
    const int*   hh_indices = (const int*)d_in[4];
    const int*   ih_indices = (const int*)d_in[5];
    float* out = (float*)d_out;

    char* ws = (char*)d_ws;
    float*  X2      = (float*)ws;  ws += align256((size_t)INSZ * 256 * 4);   // 51.2 MB
    float4* ihc     = (float4*)ws; ws += align256((size_t)HSZ * 256 * 4);    // 51.2 MB
    float4* hbuf    = (float4*)ws; ws += align256((size_t)2 * HSZ * BSZ * 4);// 3.2 MB
    int*    hh_ptr  = (int*)ws;    ws += align256((size_t)(HSZ + 1) * 4);
    int*    hh_cnt  = (int*)ws;    ws += align256((size_t)HSZ * 4);
    int*    hh_fill = (int*)ws;    ws += align256((size_t)HSZ * 4);
    float2* hh_cv   = (float2*)ws; ws += align256((size_t)NNZc * 8);         // 6.4 MB
    int*    ih_ptr  = (int*)ws;    ws += align256((size_t)(HSZ + 1) * 4);
    int*    ih_cnt  = (int*)ws;    ws += align256((size_t)HSZ * 4);
    int*    ih_fill = (int*)ws;    ws += align256((size_t)HSZ * 4);
    float2* ih_cv   = (float2*)ws; ws += align256((size_t)NNZc * 8);         // 6.4 MB
    int*    partials= (int*)ws;    ws += align256((size_t)128 * 4);

    hipMemsetAsync(hh_cnt, 0, (size_t)HSZ * 4, stream);
    hipMemsetAsync(ih_cnt, 0, (size_t)HSZ * 4, stream);
    hipMemsetAsync(hbuf, 0, (size_t)HSZ * BSZ * 4, stream);   // h0 = 0

    int histBlocks = (2 * NNZc + 255) / 256;
    hist_kernel<<<histBlocks, 256, 0, stream>>>(hh_indices, ih_indices, hh_cnt, ih_cnt);
    scanA_kernel<<<dim3(NCHUNK, 2), 1024, 0, stream>>>(hh_cnt, ih_cnt, hh_ptr, ih_ptr, partials);
    scanB_kernel<<<1, 64, 0, stream>>>(partials);
    scanC_kernel<<<dim3((HSZ + 255) / 256, 2), 256, 0, stream>>>(hh_ptr, hh_fill, ih_ptr, ih_fill, partials);
    scatter_kernel<<<histBlocks, 256, 0, stream>>>(hh_indices, hh_values, ih_indices, ih_values,
                                                   hh_fill, ih_fill, hh_cv, ih_cv);

    transpose_x2<<<(INSZ + 63) / 64, 256, 64 * 257 * 4, stream>>>(x, X2);
    ihc_kernel<<<(HSZ + 3) / 4, 256, 0, stream>>>(ih_ptr, ih_cv, hh_bias, (const float4*)X2, ihc);

    int stepBlocks = (2 * HSZ + 255) / 256;
    for (int t = 0; t < TSZ; ++t) {
        float4* hin  = hbuf + (size_t)(t & 1) * HSZ * 2;
        float4* hout = hbuf + (size_t)((t + 1) & 1) * HSZ * 2;
        const float4* ihc_t = ihc + (size_t)t * 2 * HSZ;
        step_kernel<<<stepBlocks, 256, 0, stream>>>(hh_ptr, hh_cv, ihc_t, hin, hout, out, t);
    }
}

// Round 3
// 833.630 us; speedup vs baseline: 1.4393x; 1.1139x over previous
//
#include <hip/hip_runtime.h>
#include <math.h>

#define HSZ 50000
#define INSZ 50000
#define NNZc 800000
#define BSZ 8
#define TSZ 32
#define NCHUNK 49   // ceil(HSZ/1024)

// ---------------- CSR build ----------------

__global__ void hist_kernel(const int* __restrict__ hh_idx, const int* __restrict__ ih_idx,
                            int* __restrict__ hh_cnt, int* __restrict__ ih_cnt) {
    int i = blockIdx.x * blockDim.x + threadIdx.x;
    if (i < NNZc) {
        atomicAdd(&hh_cnt[hh_idx[i]], 1);
    } else if (i < 2 * NNZc) {
        atomicAdd(&ih_cnt[ih_idx[i - NNZc]], 1);
    }
}

// Per-chunk exclusive scan; chunk totals to partials[mat*64 + chunk].
__global__ void scanA_kernel(const int* __restrict__ cnt_hh, const int* __restrict__ cnt_ih,
                             int* __restrict__ ptr_hh, int* __restrict__ ptr_ih,
                             int* __restrict__ partials) {
    const int* cnt = blockIdx.y ? cnt_ih : cnt_hh;
    int* ptr = blockIdx.y ? ptr_ih : ptr_hh;
    __shared__ int sm[1024];
    int tid = threadIdx.x;
    int idx = blockIdx.x * 1024 + tid;
    int v = (idx < HSZ) ? cnt[idx] : 0;
    sm[tid] = v;
    __syncthreads();
    int x = v;
    for (int off = 1; off < 1024; off <<= 1) {
        int y = (tid >= off) ? sm[tid - off] : 0;
        __syncthreads();
        x += y;
        sm[tid] = x;
        __syncthreads();
    }
    if (idx < HSZ) ptr[idx] = x - v;
    if (tid == 1023) partials[blockIdx.y * 64 + blockIdx.x] = x;
}

// One wave scans the chunk totals (exclusive), both matrices.
__global__ void scanB_kernel(int* __restrict__ partials) {
    int lane = threadIdx.x;
    for (int m = 0; m < 2; ++m) {
        int v = (lane < NCHUNK) ? partials[m * 64 + lane] : 0;
        int orig = v;
        for (int off = 1; off < 64; off <<= 1) {
            int y = __shfl_up(v, off, 64);
            if (lane >= off) v += y;
        }
        if (lane < NCHUNK) partials[m * 64 + lane] = v - orig;
    }
}

__global__ void scanC_kernel(int* __restrict__ ptr_hh, int* __restrict__ fill_hh,
                             int* __restrict__ ptr_ih, int* __restrict__ fill_ih,
                             const int* __restrict__ partials) {
    int mat = blockIdx.y;
    int* ptr  = mat ? ptr_ih : ptr_hh;
    int* fill = mat ? fill_ih : fill_hh;
    int i = blockIdx.x * 256 + threadIdx.x;
    if (i < HSZ) {
        int v = ptr[i] + partials[mat * 64 + (i >> 10)];
        ptr[i] = v;
        fill[i] = v;
    }
    if (i == 0) ptr[HSZ] = NNZc;
}

// Scatter into packed (col, val) pairs: one 8B load per nnz downstream.
__global__ void scatter_kernel(const int* __restrict__ hh_idx, const float* __restrict__ hh_v,
                               const int* __restrict__ ih_idx, const float* __restrict__ ih_v,
                               int* __restrict__ hh_fill, int* __restrict__ ih_fill,
                               float2* __restrict__ hh_cv, float2* __restrict__ ih_cv) {
    int i = blockIdx.x * blockDim.x + threadIdx.x;
    if (i < NNZc) {
        int r = hh_idx[i];
        int c = hh_idx[NNZc + i];
        int pos = atomicAdd(&hh_fill[r], 1);
        hh_cv[pos] = make_float2(__int_as_float(c), hh_v[i]);
    } else if (i < 2 * NNZc) {
        int k = i - NNZc;
        int r = ih_idx[k];
        int c = ih_idx[NNZc + k];
        int pos = atomicAdd(&ih_fill[r], 1);
        ih_cv[pos] = make_float2(__int_as_float(c), ih_v[k]);
    }
}

// ---------------- transpose: x (B,T,IN) -> X2 (IN, 256) where col = t*8+b ----------------

__global__ void transpose_x2(const float* __restrict__ x, float* __restrict__ X2) {
    extern __shared__ float tile[];   // 64 * 257 floats
    int i0 = blockIdx.x * 64;
    int tid = threadIdx.x;
    int il = tid & 63, tg = tid >> 6;
    for (int k = 0; k < 64; ++k) {
        int tb = k * 4 + tg;                 // 0..255
        int t = tb >> 3, b = tb & 7;
        int i = i0 + il;
        float v = (i < INSZ) ? x[((size_t)b * TSZ + t) * INSZ + i] : 0.f;
        tile[il * 257 + tb] = v;             // stride 257: conflict-free
    }
    __syncthreads();
    for (int k = 0; k < 64; ++k) {
        int i = i0 + k;
        if (i < INSZ) X2[(size_t)i * 256 + tid] = tile[k * 257 + tid];
    }
}

// ---------------- ihc: one wave per row, 1KB coalesced X2 row reads ----------------
// ihc layout: float4 array, element [(t*2+q)*HSZ + r] holds b = q*4..q*4+3 for (t,r).
// lane covers tb = lane*4..lane*4+3  =>  t*2+q == lane. Bias folded in here.

__global__ void ihc_kernel(const int* __restrict__ ptr, const float2* __restrict__ cv,
                           const float* __restrict__ bias, const float4* __restrict__ X2,
                           float4* __restrict__ ihc) {
    int r = (blockIdx.x << 2) + (threadIdx.x >> 6);
    int lane = threadIdx.x & 63;
    if (r >= HSZ) return;
    int s = ptr[r], e = ptr[r + 1];
    s = __builtin_amdgcn_readfirstlane(s);   // wave-uniform -> scalar loop, s_load colval
    e = __builtin_amdgcn_readfirstlane(e);
    float4 acc = make_float4(0.f, 0.f, 0.f, 0.f);
    for (int j = s; j < e; ++j) {
        float2 c_v = cv[j];
        int c = __float_as_int(c_v.x);
        float v = c_v.y;
        float4 xv = X2[((size_t)c << 6) + lane];
        acc.x = fmaf(v, xv.x, acc.x);
        acc.y = fmaf(v, xv.y, acc.y);
        acc.z = fmaf(v, xv.z, acc.z);
        acc.w = fmaf(v, xv.w, acc.w);
    }
    float bb = bias[r];
    acc.x += bb; acc.y += bb; acc.z += bb; acc.w += bb;
    ihc[(size_t)lane * HSZ + r] = acc;
}

// ---------------- recurrence step ----------------
// 4 lanes per (row, b-half): lane sub takes nnz j = s+sub, s+sub+4, ...
// then 2-round shfl_xor reduction within the 4-lane group.

__device__ __forceinline__ float fast_tanh(float x) {
    float e = __expf(2.0f * x);
    return 1.0f - __fdividef(2.0f, e + 1.0f);
}

__global__ void step_kernel(const int* __restrict__ ptr, const float2* __restrict__ cv,
                            const float4* __restrict__ ihc_t, const float4* __restrict__ h_in,
                            float4* __restrict__ h_out, float* __restrict__ out, int t) {
    int gid = blockIdx.x * 256 + threadIdx.x;    // gid = (item<<2) | sub
    if (gid >= 8 * HSZ) return;
    int sub  = gid & 3;
    int item = gid >> 2;                         // item = r*2 + q
    int r = item >> 1, q = item & 1;
    int s = ptr[r], e = ptr[r + 1];
    float4 acc = make_float4(0.f, 0.f, 0.f, 0.f);
    for (int j = s + sub; j < e; j += 4) {
        float2 c_v = cv[j];                      // 4 consecutive lanes: 32B coalesced
        int c = __float_as_int(c_v.x);
        float v = c_v.y;
        float4 hv = h_in[((size_t)c << 1) + q];
        acc.x = fmaf(v, hv.x, acc.x);
        acc.y = fmaf(v, hv.y, acc.y);
        acc.z = fmaf(v, hv.z, acc.z);
        acc.w = fmaf(v, hv.w, acc.w);
    }
    // reduce across the 4-lane group
    acc.x += __shfl_xor(acc.x, 1); acc.y += __shfl_xor(acc.y, 1);
    acc.z += __shfl_xor(acc.z, 1); acc.w += __shfl_xor(acc.w, 1);
    acc.x += __shfl_xor(acc.x, 2); acc.y += __shfl_xor(acc.y, 2);
    acc.z += __shfl_xor(acc.z, 2); acc.w += __shfl_xor(acc.w, 2);
    float4 base = ihc_t[q * HSZ + r];            // bias folded in; broadcast load
    float4 h;
    h.x = fast_tanh(acc.x + base.x);
    h.y = fast_tanh(acc.y + base.y);
    h.z = fast_tanh(acc.z + base.z);
    h.w = fast_tanh(acc.w + base.w);
    if (sub == 0) {
        h_out[item] = h;
        int b0 = q << 2;
        out[((size_t)(b0 + 0) * TSZ + t) * HSZ + r] = h.x;
        out[((size_t)(b0 + 1) * TSZ + t) * HSZ + r] = h.y;
        out[((size_t)(b0 + 2) * TSZ + t) * HSZ + r] = h.z;
        out[((size_t)(b0 + 3) * TSZ + t) * HSZ + r] = h.w;
    }
}

// ---------------- launch ----------------

static inline size_t align256(size_t x) { return (x + 255) & ~(size_t)255; }

extern "C" void kernel_launch(void* const* d_in, const int* in_sizes, int n_in,
                              void* d_out, int out_size, void* d_ws, size_t ws_size,
                              hipStream_t stream) {
    const float* x          = (const float*)d_in[0];
    const float* hh_values  = (const float*)d_in[1];
    const float* hh_bias    = (const float*)d_in[2];
    const float* ih_values  = (const float*)d_in[3];
    const int*   hh_indices = (const int*)d_in[4];
    const int*   ih_indices = (const int*)d_in[5];
    float* out = (float*)d_out;

    char* ws = (char*)d_ws;
    float*  X2      = (float*)ws;  ws += align256((size_t)INSZ * 256 * 4);   // 51.2 MB
    float4* ihc     = (float4*)ws; ws += align256((size_t)HSZ * 256 * 4);    // 51.2 MB
    float4* hbuf    = (float4*)ws; ws += align256((size_t)2 * HSZ * BSZ * 4);// 3.2 MB
    int*    hh_ptr  = (int*)ws;    ws += align256((size_t)(HSZ + 1) * 4);
    int*    hh_cnt  = (int*)ws;    ws += align256((size_t)HSZ * 4);
    int*    hh_fill = (int*)ws;    ws += align256((size_t)HSZ * 4);
    float2* hh_cv   = (float2*)ws; ws += align256((size_t)NNZc * 8);         // 6.4 MB
    int*    ih_ptr  = (int*)ws;    ws += align256((size_t)(HSZ + 1) * 4);
    int*    ih_cnt  = (int*)ws;    ws += align256((size_t)HSZ * 4);
    int*    ih_fill = (int*)ws;    ws += align256((size_t)HSZ * 4);
    float2* ih_cv   = (float2*)ws; ws += align256((size_t)NNZc * 8);         // 6.4 MB
    int*    partials= (int*)ws;    ws += align256((size_t)128 * 4);

    hipMemsetAsync(hh_cnt, 0, (size_t)HSZ * 4, stream);
    hipMemsetAsync(ih_cnt, 0, (size_t)HSZ * 4, stream);
    hipMemsetAsync(hbuf, 0, (size_t)HSZ * BSZ * 4, stream);   // h0 = 0

    int histBlocks = (2 * NNZc + 255) / 256;
    hist_kernel<<<histBlocks, 256, 0, stream>>>(hh_indices, ih_indices, hh_cnt, ih_cnt);
    scanA_kernel<<<dim3(NCHUNK, 2), 1024, 0, stream>>>(hh_cnt, ih_cnt, hh_ptr, ih_ptr, partials);
    scanB_kernel<<<1, 64, 0, stream>>>(partials);
    scanC_kernel<<<dim3((HSZ + 255) / 256, 2), 256, 0, stream>>>(hh_ptr, hh_fill, ih_ptr, ih_fill, partials);
    scatter_kernel<<<histBlocks, 256, 0, stream>>>(hh_indices, hh_values, ih_indices, ih_values,
                                                   hh_fill, ih_fill, hh_cv, ih_cv);

    transpose_x2<<<(INSZ + 63) / 64, 256, 64 * 257 * 4, stream>>>(x, X2);
    ihc_kernel<<<(HSZ + 3) / 4, 256, 0, stream>>>(ih_ptr, ih_cv, hh_bias, (const float4*)X2, ihc);

    int stepBlocks = (8 * HSZ + 255) / 256;
    for (int t = 0; t < TSZ; ++t) {
        float4* hin  = hbuf + (size_t)(t & 1) * HSZ * 2;
        float4* hout = hbuf + (size_t)((t + 1) & 1) * HSZ * 2;
        const float4* ihc_t = ihc + (size_t)t * 2 * HSZ;
        step_kernel<<<stepBlocks, 256, 0, stream>>>(hh_ptr, hh_cv, ihc_t, hin, hout, out, t);
    }
}

// Round 4
// 714.342 us; speedup vs baseline: 1.6797x; 1.1670x over previous
//
#include <hip/hip_runtime.h>
#include <math.h>

#define HSZ 50000
#define INSZ 50000
#define NNZc 800000
#define BSZ 8
#define TSZ 32
#define NCHUNK 49   // ceil(HSZ/1024)

typedef _Float16 half8 __attribute__((ext_vector_type(8)));
typedef _Float16 half4 __attribute__((ext_vector_type(4)));

// ---------------- CSR build ----------------

__global__ void hist_kernel(const int* __restrict__ hh_idx, const int* __restrict__ ih_idx,
                            int* __restrict__ hh_cnt, int* __restrict__ ih_cnt) {
    int i = blockIdx.x * blockDim.x + threadIdx.x;
    if (i < NNZc) {
        atomicAdd(&hh_cnt[hh_idx[i]], 1);
    } else if (i < 2 * NNZc) {
        atomicAdd(&ih_cnt[ih_idx[i - NNZc]], 1);
    }
}

__global__ void scanA_kernel(const int* __restrict__ cnt_hh, const int* __restrict__ cnt_ih,
                             int* __restrict__ ptr_hh, int* __restrict__ ptr_ih,
                             int* __restrict__ partials) {
    const int* cnt = blockIdx.y ? cnt_ih : cnt_hh;
    int* ptr = blockIdx.y ? ptr_ih : ptr_hh;
    __shared__ int sm[1024];
    int tid = threadIdx.x;
    int idx = blockIdx.x * 1024 + tid;
    int v = (idx < HSZ) ? cnt[idx] : 0;
    sm[tid] = v;
    __syncthreads();
    int x = v;
    for (int off = 1; off < 1024; off <<= 1) {
        int y = (tid >= off) ? sm[tid - off] : 0;
        __syncthreads();
        x += y;
        sm[tid] = x;
        __syncthreads();
    }
    if (idx < HSZ) ptr[idx] = x - v;
    if (tid == 1023) partials[blockIdx.y * 64 + blockIdx.x] = x;
}

__global__ void scanB_kernel(int* __restrict__ partials) {
    int lane = threadIdx.x;
    for (int m = 0; m < 2; ++m) {
        int v = (lane < NCHUNK) ? partials[m * 64 + lane] : 0;
        int orig = v;
        for (int off = 1; off < 64; off <<= 1) {
            int y = __shfl_up(v, off, 64);
            if (lane >= off) v += y;
        }
        if (lane < NCHUNK) partials[m * 64 + lane] = v - orig;
    }
}

__global__ void scanC_kernel(int* __restrict__ ptr_hh, int* __restrict__ fill_hh,
                             int* __restrict__ ptr_ih, int* __restrict__ fill_ih,
                             const int* __restrict__ partials) {
    int mat = blockIdx.y;
    int* ptr  = mat ? ptr_ih : ptr_hh;
    int* fill = mat ? fill_ih : fill_hh;
    int i = blockIdx.x * 256 + threadIdx.x;
    if (i < HSZ) {
        int v = ptr[i] + partials[mat * 64 + (i >> 10)];
        ptr[i] = v;
        fill[i] = v;
    }
    if (i == 0) ptr[HSZ] = NNZc;
}

__global__ void scatter_kernel(const int* __restrict__ hh_idx, const float* __restrict__ hh_v,
                               const int* __restrict__ ih_idx, const float* __restrict__ ih_v,
                               int* __restrict__ hh_fill, int* __restrict__ ih_fill,
                               float2* __restrict__ hh_cv, float2* __restrict__ ih_cv) {
    int i = blockIdx.x * blockDim.x + threadIdx.x;
    if (i < NNZc) {
        int r = hh_idx[i];
        int c = hh_idx[NNZc + i];
        int pos = atomicAdd(&hh_fill[r], 1);
        hh_cv[pos] = make_float2(__int_as_float(c), hh_v[i]);
    } else if (i < 2 * NNZc) {
        int k = i - NNZc;
        int r = ih_idx[k];
        int c = ih_idx[NNZc + k];
        int pos = atomicAdd(&ih_fill[r], 1);
        ih_cv[pos] = make_float2(__int_as_float(c), ih_v[k]);
    }
}

// ---------------- transpose: x (B,T,IN) -> X2h (IN, 256) fp16, col = t*8+b ----------------

__global__ void transpose_x2(const float* __restrict__ x, _Float16* __restrict__ X2h) {
    extern __shared__ float tile[];   // 64 * 257 floats
    int i0 = blockIdx.x * 64;
    int tid = threadIdx.x;
    int il = tid & 63, tg = tid >> 6;
    for (int k = 0; k < 64; ++k) {
        int tb = k * 4 + tg;                 // 0..255
        int t = tb >> 3, b = tb & 7;
        int i = i0 + il;
        float v = (i < INSZ) ? x[((size_t)b * TSZ + t) * INSZ + i] : 0.f;
        tile[il * 257 + tb] = v;             // stride 257: conflict-free
    }
    __syncthreads();
    for (int k = 0; k < 64; ++k) {
        int i = i0 + k;
        if (i < INSZ) X2h[(size_t)i * 256 + tid] = (_Float16)tile[k * 257 + tid];
    }
}

// ---------------- ihc: one wave per row; X2h fp16 row reads (512B/nnz) ----------------
// ihc layout (half4 units): [(r<<6) + lane], lane = t*2+q. Bias folded in.

__global__ void ihc_kernel(const int* __restrict__ ptr, const float2* __restrict__ cv,
                           const float* __restrict__ bias, const half4* __restrict__ X2h,
                           half4* __restrict__ ihc) {
    int r = (blockIdx.x << 2) + (threadIdx.x >> 6);
    int lane = threadIdx.x & 63;
    if (r >= HSZ) return;
    int s = ptr[r], e = ptr[r + 1];
    s = __builtin_amdgcn_readfirstlane(s);
    e = __builtin_amdgcn_readfirstlane(e);
    float4 acc = make_float4(0.f, 0.f, 0.f, 0.f);
    int j = s;
    for (; j + 1 < e; j += 2) {              // unroll-2: two 512B loads in flight
        float2 a = cv[j];
        float2 b = cv[j + 1];
        half4 x0 = X2h[((size_t)__float_as_int(a.x) << 6) + lane];
        half4 x1 = X2h[((size_t)__float_as_int(b.x) << 6) + lane];
        acc.x = fmaf(a.y, (float)x0[0], acc.x);
        acc.y = fmaf(a.y, (float)x0[1], acc.y);
        acc.z = fmaf(a.y, (float)x0[2], acc.z);
        acc.w = fmaf(a.y, (float)x0[3], acc.w);
        acc.x = fmaf(b.y, (float)x1[0], acc.x);
        acc.y = fmaf(b.y, (float)x1[1], acc.y);
        acc.z = fmaf(b.y, (float)x1[2], acc.z);
        acc.w = fmaf(b.y, (float)x1[3], acc.w);
    }
    if (j < e) {
        float2 a = cv[j];
        half4 x0 = X2h[((size_t)__float_as_int(a.x) << 6) + lane];
        acc.x = fmaf(a.y, (float)x0[0], acc.x);
        acc.y = fmaf(a.y, (float)x0[1], acc.y);
        acc.z = fmaf(a.y, (float)x0[2], acc.z);
        acc.w = fmaf(a.y, (float)x0[3], acc.w);
    }
    float bb = bias[r];
    half4 o;
    o[0] = (_Float16)(acc.x + bb);
    o[1] = (_Float16)(acc.y + bb);
    o[2] = (_Float16)(acc.z + bb);
    o[3] = (_Float16)(acc.w + bb);
    ihc[((size_t)r << 6) + lane] = o;        // wave writes 512B contiguous
}

// ---------------- recurrence step ----------------
// thread = (r, sub), sub in [0,4): one 16B half8 gather per nnz covers all 8 batches.

__device__ __forceinline__ float fast_tanh(float x) {
    float e = __expf(2.0f * x);
    return 1.0f - __fdividef(2.0f, e + 1.0f);
}

__global__ void step_kernel(const int* __restrict__ ptr, const float2* __restrict__ cv,
                            const half8* __restrict__ ihc8, const half8* __restrict__ h_in,
                            half8* __restrict__ h_out, float* __restrict__ out, int t) {
    int gid = blockIdx.x * 256 + threadIdx.x;    // gid = r*4 + sub
    if (gid >= 4 * HSZ) return;
    int sub = gid & 3;
    int r = gid >> 2;
    int s = ptr[r], e = ptr[r + 1];
    half8 base8 = ihc8[(size_t)r * 32 + t];      // independent load, issues early
    float acc0 = 0.f, acc1 = 0.f, acc2 = 0.f, acc3 = 0.f;
    float acc4 = 0.f, acc5 = 0.f, acc6 = 0.f, acc7 = 0.f;
    for (int j = s + sub; j < e; j += 4) {
        float2 c_v = cv[j];                      // 4 consecutive lanes: 32B coalesced
        float v = c_v.y;
        half8 hv = h_in[(size_t)__float_as_int(c_v.x)];
        acc0 = fmaf(v, (float)hv[0], acc0);
        acc1 = fmaf(v, (float)hv[1], acc1);
        acc2 = fmaf(v, (float)hv[2], acc2);
        acc3 = fmaf(v, (float)hv[3], acc3);
        acc4 = fmaf(v, (float)hv[4], acc4);
        acc5 = fmaf(v, (float)hv[5], acc5);
        acc6 = fmaf(v, (float)hv[6], acc6);
        acc7 = fmaf(v, (float)hv[7], acc7);
    }
    // reduce across the 4-lane group
    acc0 += __shfl_xor(acc0, 1); acc1 += __shfl_xor(acc1, 1);
    acc2 += __shfl_xor(acc2, 1); acc3 += __shfl_xor(acc3, 1);
    acc4 += __shfl_xor(acc4, 1); acc5 += __shfl_xor(acc5, 1);
    acc6 += __shfl_xor(acc6, 1); acc7 += __shfl_xor(acc7, 1);
    acc0 += __shfl_xor(acc0, 2); acc1 += __shfl_xor(acc1, 2);
    acc2 += __shfl_xor(acc2, 2); acc3 += __shfl_xor(acc3, 2);
    acc4 += __shfl_xor(acc4, 2); acc5 += __shfl_xor(acc5, 2);
    acc6 += __shfl_xor(acc6, 2); acc7 += __shfl_xor(acc7, 2);
    if (sub == 0) {
        float h0 = fast_tanh(acc0 + (float)base8[0]);
        float h1 = fast_tanh(acc1 + (float)base8[1]);
        float h2 = fast_tanh(acc2 + (float)base8[2]);
        float h3 = fast_tanh(acc3 + (float)base8[3]);
        float h4 = fast_tanh(acc4 + (float)base8[4]);
        float h5 = fast_tanh(acc5 + (float)base8[5]);
        float h6 = fast_tanh(acc6 + (float)base8[6]);
        float h7 = fast_tanh(acc7 + (float)base8[7]);
        half8 hh;
        hh[0] = (_Float16)h0; hh[1] = (_Float16)h1;
        hh[2] = (_Float16)h2; hh[3] = (_Float16)h3;
        hh[4] = (_Float16)h4; hh[5] = (_Float16)h5;
        hh[6] = (_Float16)h6; hh[7] = (_Float16)h7;
        h_out[r] = hh;
        out[((size_t)0 * TSZ + t) * HSZ + r] = h0;
        out[((size_t)1 * TSZ + t) * HSZ + r] = h1;
        out[((size_t)2 * TSZ + t) * HSZ + r] = h2;
        out[((size_t)3 * TSZ + t) * HSZ + r] = h3;
        out[((size_t)4 * TSZ + t) * HSZ + r] = h4;
        out[((size_t)5 * TSZ + t) * HSZ + r] = h5;
        out[((size_t)6 * TSZ + t) * HSZ + r] = h6;
        out[((size_t)7 * TSZ + t) * HSZ + r] = h7;
    }
}

// ---------------- launch ----------------

static inline size_t align256(size_t x) { return (x + 255) & ~(size_t)255; }

extern "C" void kernel_launch(void* const* d_in, const int* in_sizes, int n_in,
                              void* d_out, int out_size, void* d_ws, size_t ws_size,
                              hipStream_t stream) {
    const float* x          = (const float*)d_in[0];
    const float* hh_values  = (const float*)d_in[1];
    const float* hh_bias    = (const float*)d_in[2];
    const float* ih_values  = (const float*)d_in[3];
    const int*   hh_indices = (const int*)d_in[4];
    const int*   ih_indices = (const int*)d_in[5];
    float* out = (float*)d_out;

    char* ws = (char*)d_ws;
    _Float16* X2h   = (_Float16*)ws; ws += align256((size_t)INSZ * 256 * 2);   // 25.6 MB
    half4*  ihc     = (half4*)ws;  ws += align256((size_t)HSZ * 256 * 2);      // 25.6 MB
    half8*  hbuf    = (half8*)ws;  ws += align256((size_t)2 * HSZ * 16);       // 1.6 MB
    int*    hh_ptr  = (int*)ws;    ws += align256((size_t)(HSZ + 1) * 4);
    int*    hh_cnt  = (int*)ws;    ws += align256((size_t)HSZ * 4);
    int*    hh_fill = (int*)ws;    ws += align256((size_t)HSZ * 4);
    float2* hh_cv   = (float2*)ws; ws += align256((size_t)NNZc * 8);           // 6.4 MB
    int*    ih_ptr  = (int*)ws;    ws += align256((size_t)(HSZ + 1) * 4);
    int*    ih_cnt  = (int*)ws;    ws += align256((size_t)HSZ * 4);
    int*    ih_fill = (int*)ws;    ws += align256((size_t)HSZ * 4);
    float2* ih_cv   = (float2*)ws; ws += align256((size_t)NNZc * 8);           // 6.4 MB
    int*    partials= (int*)ws;    ws += align256((size_t)128 * 4);

    hipMemsetAsync(hh_cnt, 0, (size_t)HSZ * 4, stream);
    hipMemsetAsync(ih_cnt, 0, (size_t)HSZ * 4, stream);
    hipMemsetAsync(hbuf, 0, (size_t)HSZ * 16, stream);   // h0 = 0 (fp16 zero bits)

    int histBlocks = (2 * NNZc + 255) / 256;
    hist_kernel<<<histBlocks, 256, 0, stream>>>(hh_indices, ih_indices, hh_cnt, ih_cnt);
    scanA_kernel<<<dim3(NCHUNK, 2), 1024, 0, stream>>>(hh_cnt, ih_cnt, hh_ptr, ih_ptr, partials);
    scanB_kernel<<<1, 64, 0, stream>>>(partials);
    scanC_kernel<<<dim3((HSZ + 255) / 256, 2), 256, 0, stream>>>(hh_ptr, hh_fill, ih_ptr, ih_fill, partials);
    scatter_kernel<<<histBlocks, 256, 0, stream>>>(hh_indices, hh_values, ih_indices, ih_values,
                                                   hh_fill, ih_fill, hh_cv, ih_cv);

    transpose_x2<<<(INSZ + 63) / 64, 256, 64 * 257 * 4, stream>>>(x, X2h);
    ihc_kernel<<<(HSZ + 3) / 4, 256, 0, stream>>>(ih_ptr, ih_cv, hh_bias, (const half4*)X2h, ihc);

    int stepBlocks = (4 * HSZ + 255) / 256;
    for (int t = 0; t < TSZ; ++t) {
        half8* hin  = hbuf + (size_t)(t & 1) * HSZ;
        half8* hout = hbuf + (size_t)((t + 1) & 1) * HSZ;
        step_kernel<<<stepBlocks, 256, 0, stream>>>(hh_ptr, hh_cv, (const half8*)ihc,
                                                    hin, hout, out, t);
    }
}